// Round 5
// baseline (33.263 us; speedup 1.0000x reference)
//
#include <hip/hip_runtime.h>
#include <math.h>

#define EPSC 1.1920928955078125e-07f
#define BATCH 8388608
#define IN_FEATS 2048
#define N_W_BLOCKS 128                 // one 16-column strip each (64 groups + 64 tail strips)
#define N_BCE_BLOCKS 1024              // 64 KB of p+y each
#define TOTAL_BLOCKS (N_W_BLOCKS + N_BCE_BLOCKS)
#define BCE_ITERS 8                    // 8 * 256 float4 = 2048 float4 = 32 KB per stream

__device__ __forceinline__ float penalty_f(float x) {
    return 1.0f - __expf(-x * x) + fabsf(x);
}

// One dispatch. Blocks 0..127: own 16 whole columns of W -> col norms -> local
// penalty -> one atomicAdd. Blocks 128..1151: BCE partial -> one atomicAdd.
// No cross-block dependencies, no fences; out[0] = sum of all contributions.
__global__ __launch_bounds__(256) void fused_k(
        const float* __restrict__ p, const float* __restrict__ y,
        const float* __restrict__ W, float* __restrict__ out) {
    const int b = blockIdx.x;
    const int t = threadIdx.x;

    if (b < N_W_BLOCKS) {
        // ---- 16-column strip: cols [b*16, b*16+16), all 1024 rows (64 KB) ----
        const int colbase = b * 16;
        const int c4 = t & 3;                   // which float4 of the strip
        const int rs = t >> 2;                  // row slice 0..63
        const float4* wbase = (const float4*)(W + (size_t)rs * IN_FEATS + colbase) + c4;
        float4 a = {0.f, 0.f, 0.f, 0.f};
        #pragma unroll
        for (int it = 0; it < 16; ++it) {       // rows rs + 64*it
            float4 w = wbase[(size_t)it * 64 * (IN_FEATS / 4)];
            a.x = fmaf(w.x, w.x, a.x);
            a.y = fmaf(w.y, w.y, a.y);
            a.z = fmaf(w.z, w.z, a.z);
            a.w = fmaf(w.w, w.w, a.w);
        }
        __shared__ float lds[64][16];
        lds[rs][c4 * 4 + 0] = a.x;
        lds[rs][c4 * 4 + 1] = a.y;
        lds[rs][c4 * 4 + 2] = a.z;
        lds[rs][c4 * 4 + 3] = a.w;
        __syncthreads();

        __shared__ float ln[16];
        if (t < 16) {                           // one column per thread
            float s = 0.0f;
            #pragma unroll 8
            for (int r = 0; r < 64; ++r) s += lds[r][t];
            ln[t] = sqrtf(s);
        }
        __syncthreads();
        if (t == 0) {
            float contrib;
            if (b < 64) {                       // categorical group: f(mean of 16 norms)
                float gs = 0.0f;
                #pragma unroll
                for (int k = 0; k < 16; ++k) gs += ln[k];
                contrib = penalty_f(gs * (1.0f / 16.0f));
            } else {                            // tail strip: sum of f(norm)
                float s = 0.0f;
                #pragma unroll
                for (int k = 0; k < 16; ++k) s += penalty_f(ln[k]);
                contrib = s;
            }
            atomicAdd(out, 0.01f * contrib);
        }
    } else {
        // ---- BCE slice: contiguous 2048 float4 of p and of y (64 KB total) ----
        const int bb = b - N_W_BLOCKS;
        const float4* p4 = (const float4*)p + (size_t)bb * 2048;
        const float4* y4 = (const float4*)y + (size_t)bb * 2048;
        float acc = 0.0f;
        #pragma unroll
        for (int it = 0; it < BCE_ITERS; ++it) {
            int i = it * 256 + t;
            float4 pv = p4[i];
            float4 yv = y4[i];
            float pp[4] = {pv.x, pv.y, pv.z, pv.w};
            float yy[4] = {yv.x, yv.y, yv.z, yv.w};
            #pragma unroll
            for (int k = 0; k < 4; ++k) {
                // y is exactly 0.0 or 1.0: one BCE branch survives.
                bool pos = yy[k] > 0.5f;
                float x  = pos ? pp[k] : 1.0f - pp[k];
                float w  = pos ? 0.7f : 0.3f;
                float xc = fminf(fmaxf(x, EPSC), 1.0f - EPSC);
                acc -= w * __logf(xc);
            }
        }
        __shared__ float s[256];
        s[t] = acc;
        __syncthreads();
        #pragma unroll
        for (int o = 128; o > 0; o >>= 1) {
            if (t < o) s[t] += s[t + o];
            __syncthreads();
        }
        if (t == 0) atomicAdd(out, s[0] * (1.0f / (float)BATCH));
    }
}

extern "C" void kernel_launch(void* const* d_in, const int* in_sizes, int n_in,
                              void* d_out, int out_size, void* d_ws, size_t ws_size,
                              hipStream_t stream) {
    const float* p = (const float*)d_in[0];
    const float* y = (const float*)d_in[1];
    const float* W = (const float*)d_in[2];
    float* out = (float*)d_out;

    hipMemsetAsync(out, 0, sizeof(float), stream);   // we accumulate into out
    fused_k<<<TOTAL_BLOCKS, 256, 0, stream>>>(p, y, W, out);
}

// Round 6
// 20.633 us; speedup vs baseline: 1.6121x; 1.6121x over previous
//
#include <hip/hip_runtime.h>
#include <math.h>

#define EPSC 1.1920928955078125e-07f
#define BATCH 8388608
#define IN_FEATS 2048
#define N_W_BLOCKS 128                 // 16-column strip each: 64 group blocks + 64 tail blocks
#define N_BCE_BLOCKS 2048              // 1024 float4 of p + 1024 float4 of y each (32 KB)
#define TOTAL_BLOCKS (N_W_BLOCKS + N_BCE_BLOCKS)   // 2176
#define BCE_ITERS 4                    // 1024 float4 / 256 threads

__device__ __forceinline__ float penalty_f(float x) {
    return 1.0f - __expf(-x * x) + fabsf(x);
}

__device__ __forceinline__ float wave_reduce(float v) {
    #pragma unroll
    for (int o = 32; o > 0; o >>= 1) v += __shfl_down(v, o, 64);
    return v;
}

// Blocks 0..127: 16-column strip of W -> column norms -> LOCAL penalty -> 1 float.
// Blocks 128..2175: BCE partial over contiguous 16 KB of p and of y -> 1 float.
// No atomics, no fences, no memset: disjoint plain stores only.
__global__ __launch_bounds__(256) void partials_k(
        const float* __restrict__ p, const float* __restrict__ y,
        const float* __restrict__ W,
        float* __restrict__ bce_part,     // [2048]
        float* __restrict__ reg_part) {   // [128]
    const int b = blockIdx.x;
    const int t = threadIdx.x;

    if (b < N_W_BLOCKS) {
        // strip cols [b*16, b*16+16), rows 0..1023  (64 KB)
        const int colbase = b * 16;
        const int c4 = t & 3;                   // float4 within the 64B strip row
        const int rs = t >> 2;                  // row slice 0..63
        const float4* wbase = (const float4*)(W + (size_t)rs * IN_FEATS + colbase) + c4;
        float4 a = {0.f, 0.f, 0.f, 0.f};
        #pragma unroll
        for (int it = 0; it < 16; ++it) {       // rows rs + 64*it
            float4 w = wbase[(size_t)it * 64 * (IN_FEATS / 4)];
            a.x = fmaf(w.x, w.x, a.x);
            a.y = fmaf(w.y, w.y, a.y);
            a.z = fmaf(w.z, w.z, a.z);
            a.w = fmaf(w.w, w.w, a.w);
        }
        __shared__ float lds[64][16];
        lds[rs][c4 * 4 + 0] = a.x;
        lds[rs][c4 * 4 + 1] = a.y;
        lds[rs][c4 * 4 + 2] = a.z;
        lds[rs][c4 * 4 + 3] = a.w;
        __syncthreads();

        __shared__ float ln[16];
        if (t < 16) {
            float s = 0.0f;
            #pragma unroll 8
            for (int r = 0; r < 64; ++r) s += lds[r][t];
            ln[t] = sqrtf(s);
        }
        __syncthreads();
        if (t == 0) {
            float contrib;
            if (b < 64) {                       // categorical group: f(mean of 16 norms)
                float gs = 0.0f;
                #pragma unroll
                for (int k = 0; k < 16; ++k) gs += ln[k];
                contrib = penalty_f(gs * (1.0f / 16.0f));
            } else {                            // tail strip: sum f(norm)
                float s = 0.0f;
                #pragma unroll
                for (int k = 0; k < 16; ++k) s += penalty_f(ln[k]);
                contrib = s;
            }
            reg_part[b] = contrib;
        }
    } else {
        const int bb = b - N_W_BLOCKS;
        const float4* p4 = (const float4*)p + (size_t)bb * 1024;
        const float4* y4 = (const float4*)y + (size_t)bb * 1024;

        float4 pv[BCE_ITERS], yv[BCE_ITERS];
        #pragma unroll
        for (int it = 0; it < BCE_ITERS; ++it) {
            int i = it * 256 + t;
            pv[it] = p4[i];
            yv[it] = y4[i];
        }
        float acc = 0.0f;
        #pragma unroll
        for (int it = 0; it < BCE_ITERS; ++it) {
            float pp[4] = {pv[it].x, pv[it].y, pv[it].z, pv[it].w};
            float yy[4] = {yv[it].x, yv[it].y, yv[it].z, yv[it].w};
            #pragma unroll
            for (int k = 0; k < 4; ++k) {
                // y is exactly 0.0 or 1.0: one BCE branch survives.
                bool pos = yy[k] > 0.5f;
                float x  = pos ? pp[k] : 1.0f - pp[k];
                float w  = pos ? 0.7f : 0.3f;
                float xc = fminf(fmaxf(x, EPSC), 1.0f - EPSC);
                acc -= w * __logf(xc);
            }
        }
        acc = wave_reduce(acc);
        __shared__ float ws[4];
        if ((t & 63) == 0) ws[t >> 6] = acc;
        __syncthreads();
        if (t == 0) bce_part[bb] = ws[0] + ws[1] + ws[2] + ws[3];
    }
}

// One 256-thread block reads 2048 BCE floats + 128 reg floats -> scalar.
__global__ __launch_bounds__(256) void finalize_k(
        const float* __restrict__ bce_part,
        const float* __restrict__ reg_part,
        float* __restrict__ out) {
    const int t = threadIdx.x;
    float sb = 0.0f;
    #pragma unroll
    for (int j = 0; j < N_BCE_BLOCKS / 256; ++j)    // 8 each
        sb += bce_part[t + j * 256];
    float sr = (t < N_W_BLOCKS) ? reg_part[t] : 0.0f;

    sb = wave_reduce(sb);
    sr = wave_reduce(sr);
    __shared__ float wb[4], wr[4];
    if ((t & 63) == 0) { wb[t >> 6] = sb; wr[t >> 6] = sr; }
    __syncthreads();
    if (t == 0) {
        float B = wb[0] + wb[1] + wb[2] + wb[3];
        float R = wr[0] + wr[1] + wr[2] + wr[3];
        out[0] = B * (1.0f / (float)BATCH) + 0.01f * R;
    }
}

extern "C" void kernel_launch(void* const* d_in, const int* in_sizes, int n_in,
                              void* d_out, int out_size, void* d_ws, size_t ws_size,
                              hipStream_t stream) {
    const float* p = (const float*)d_in[0];
    const float* y = (const float*)d_in[1];
    const float* W = (const float*)d_in[2];
    float* out = (float*)d_out;

    float* bcep = (float*)d_ws;            // 2048 floats
    float* regp = bcep + N_BCE_BLOCKS;     // 128 floats

    partials_k<<<TOTAL_BLOCKS, 256, 0, stream>>>(p, y, W, bcep, regp);
    finalize_k<<<1, 256, 0, stream>>>(bcep, regp, out);
}